// Round 2
// baseline (949.291 us; speedup 1.0000x reference)
//
#include <hip/hip_runtime.h>

#define N_NODES 10000
#define N_CH    32
#define N_EDGES 160000
#define HPAD    16      // padded h row (13 used)
#define SLOTS   8       // nodes per block

__device__ __forceinline__ float dot4(float4 a, float4 b) {
    return a.x*b.x + a.y*b.y + a.z*b.z + a.w*b.w;
}

// ---------- CSR build ----------
__global__ void k_hist(const int* __restrict__ ei, int* __restrict__ deg) {
    int e = blockIdx.x * 256 + threadIdx.x;
    atomicAdd(&deg[ei[N_EDGES + e]], 1);
}

__global__ __launch_bounds__(1024) void k_scan(const int* __restrict__ deg,
                                               int* __restrict__ offs,
                                               int* __restrict__ cursor) {
    __shared__ int part[1024];
    const int t = threadIdx.x;
    const int base = t * 10;
    int s = 0;
#pragma unroll
    for (int r = 0; r < 10; ++r) { int i = base + r; if (i < N_NODES) s += deg[i]; }
    part[t] = s;
    __syncthreads();
    for (int off = 1; off < 1024; off <<= 1) {
        int v = (t >= off) ? part[t - off] : 0;
        __syncthreads();
        part[t] += v;
        __syncthreads();
    }
    int run = (t > 0) ? part[t - 1] : 0;
#pragma unroll
    for (int r = 0; r < 10; ++r) {
        int i = base + r;
        if (i < N_NODES) { offs[i] = run; cursor[i] = run; run += deg[i]; }
    }
    if (t == 0) offs[N_NODES] = N_EDGES;
}

__global__ void k_scatter(const int* __restrict__ ei, const float* __restrict__ pos,
                          int* __restrict__ cursor, int* __restrict__ ssrc,
                          float4* __restrict__ us4) {
    int e = blockIdx.x * 256 + threadIdx.x;
    int s = ei[e], d = ei[N_EDGES + e];
    float rx = pos[d*3+0] - pos[s*3+0];
    float ry = pos[d*3+1] - pos[s*3+1];
    float rz = pos[d*3+2] - pos[s*3+2];
    float inv = 1.0f / (sqrtf(rx*rx + ry*ry + rz*rz) + 1e-9f);
    int p = atomicAdd(&cursor[d], 1);
    ssrc[p] = s;
    us4[p] = make_float4(rx*inv, ry*inv, rz*inv, 0.f);
}

// ---------- gather + W-contraction + messages -> msg[N][13][32] ----------
// Symmetric-distinct basis d in 0..9: {1, x,y,z, xx,xy,xz,yy,yz,zz}
// m(0..12) -> d map: {0, 1,2,3, 4,5,6, 5,7,8, 6,8,9}
template<int LAYER>
__global__ __launch_bounds__(256, 4) void k_gather(
    const float* __restrict__ hPrev,     // [N][32][HPAD] (LAYER==1 only)
    const float* __restrict__ emb_w,     // [32]
    const int* __restrict__ ssrc,        // [E] dst-sorted src ids
    const float4* __restrict__ us4,      // [E] dst-sorted unit vectors
    const int* __restrict__ offs,        // [N+1]
    const float* __restrict__ W_ab,      // [2][3][3][32][32]
    const float* __restrict__ ws_w,      // [2][3][3][32]
    float* __restrict__ msg)             // [N][13][32]
{
    constexpr int AMAX = (LAYER == 0) ? 1 : 3;
    __shared__ __align__(16) float Tlds[SLOTS * AMAX * 10 * 32];

    const int slot = threadIdx.x >> 5;
    const int j    = threadIdx.x & 31;
    const int node = blockIdx.x * SLOTS + slot;

    const int e0 = offs[node], e1 = offs[node + 1];

    // ================= gather phase =================
    if (LAYER == 0) {
        // h0 rank-0 == emb (same every node): T0[d] = emb_j * sum_e up_d
        float U[10];
#pragma unroll
        for (int d = 0; d < 10; ++d) U[d] = 0.f;
        for (int idx = e0; idx < e1; ++idx) {
            const float4 u = us4[idx];
            U[0] += 1.f;
            U[1] += u.x;      U[2] += u.y;      U[3] += u.z;
            U[4] += u.x*u.x;  U[5] += u.x*u.y;  U[6] += u.x*u.z;
            U[7] += u.y*u.y;  U[8] += u.y*u.z;  U[9] += u.z*u.z;
        }
        const float s0 = emb_w[j];
#pragma unroll
        for (int d = 0; d < 10; ++d)
            Tlds[(slot * 10 + d) * 32 + j] = s0 * U[d];
    } else {
        float T0[10], T1[10], T2[10];
#pragma unroll
        for (int d = 0; d < 10; ++d) { T0[d] = 0.f; T1[d] = 0.f; T2[d] = 0.f; }
#pragma unroll 2
        for (int idx = e0; idx < e1; ++idx) {
            const int src = ssrc[idx];
            const float4 u = us4[idx];
            const float* hr = hPrev + ((size_t)(src * N_CH + j)) * HPAD;
            const float4 a0 = *(const float4*)(hr);
            const float4 a1 = *(const float4*)(hr + 4);
            const float4 a2 = *(const float4*)(hr + 8);
            const float h12 = hr[12];

            const float xx = u.x*u.x, xy = u.x*u.y, xz = u.x*u.z;
            const float yy = u.y*u.y, yz = u.y*u.z, zz = u.z*u.z;
            float up[10];
            up[0] = 1.f; up[1] = u.x; up[2] = u.y; up[3] = u.z;
            up[4] = xx; up[5] = xy; up[6] = xz; up[7] = yy; up[8] = yz; up[9] = zz;

            const float s0 = a0.x;
            const float s1 = a0.y*u.x + a0.z*u.y + a0.w*u.z;
            const float s2 = a1.x*xx + (a1.y + a1.w)*xy + (a1.z + a2.z)*xz
                           + a2.x*yy + (a2.y + a2.w)*yz + h12*zz;
#pragma unroll
            for (int d = 0; d < 10; ++d) {
                T0[d] += s0 * up[d];
                T1[d] += s1 * up[d];
                T2[d] += s2 * up[d];
            }
        }
#pragma unroll
        for (int d = 0; d < 10; ++d) {
            Tlds[((slot * 3 + 0) * 10 + d) * 32 + j] = T0[d];
            Tlds[((slot * 3 + 1) * 10 + d) * 32 + j] = T1[d];
            Tlds[((slot * 3 + 2) * 10 + d) * 32 + j] = T2[d];
        }
    }

    __syncthreads();   // cross-lane Tlds reads below

    // ================= W contraction (W_ab straight from L2) =================
    float acc[10];
#pragma unroll
    for (int d = 0; d < 10; ++d) acc[d] = 0.f;

#pragma unroll
    for (int c = 0; c < 3; ++c) {
        const int dlo = (c == 0) ? 0 : ((c == 1) ? 1 : 4);
        const int dhi = (c == 0) ? 1 : ((c == 1) ? 4 : 10);
#pragma unroll
        for (int a = 0; a < AMAX; ++a) {
            // W_ab[LAYER][c][a][j][0..31] — 128 B contiguous per lane, L2-resident
            const float* wrow = W_ab + (((size_t)((LAYER * 3 + c) * 3 + a)) << 10) + (j << 5);
#pragma unroll
            for (int k4 = 0; k4 < 8; ++k4) {
                const float4 w4 = *(const float4*)(wrow + k4 * 4);
                for (int d = dlo; d < dhi; ++d) {
                    const float4 t4 = *(const float4*)&Tlds[((slot * AMAX + a) * 10 + d) * 32 + k4 * 4];
                    acc[d] += dot4(w4, t4);
                }
            }
        }
    }

    // ================= messages -> global msg =================
    const float s0n = acc[0];
    const float s0sq = s0n * s0n;
    float poly[3];
#pragma unroll
    for (int c = 0; c < 3; ++c) {
        const float* wsp = ws_w + ((size_t)((LAYER * 3 + c) * 3)) * 32 + j;
        poly[c] = wsp[0] + wsp[32] * s0n + wsp[64] * s0sq;
    }
    {
        const int mExp[13] = {0, 1, 2, 3, 4, 5, 6, 5, 7, 8, 6, 8, 9};
#pragma unroll
        for (int m = 0; m < 13; ++m) {
            const float p = (m == 0) ? poly[0] : ((m < 4) ? poly[1] : poly[2]);
            msg[((size_t)node * 13 + m) * 32 + j] = p * acc[mExp[m]];
        }
    }
}

// ---------- pure streaming update: out = CW.h_old + MW.msg ----------
template<int LAYER>
__global__ __launch_bounds__(256, 4) void k_update(
    const float* __restrict__ hPrev,     // [N][32][HPAD] (LAYER==1 only)
    const float* __restrict__ emb_w,     // [32]
    const float* __restrict__ msg,       // [N][13][32]
    const float* __restrict__ cw,        // [2][3][N][32][32]
    const float* __restrict__ mw,        // [2][3][N][32][32]
    float* __restrict__ hOut,
    const int outStride)
{
    constexpr int MSZ = SLOTS * 13 * 32;
    constexpr int HSZ = (LAYER == 0) ? 32 : MSZ;
    __shared__ __align__(16) float hls[HSZ];
    __shared__ __align__(16) float mls[MSZ];

    const int slot = threadIdx.x >> 5;
    const int j    = threadIdx.x & 31;
    const int node = blockIdx.x * SLOTS + slot;

    // msg -> LDS (coalesced 128B per m per slot)
#pragma unroll
    for (int m = 0; m < 13; ++m)
        mls[(slot * 13 + m) * 32 + j] = msg[((size_t)node * 13 + m) * 32 + j];

    // h_old -> LDS
    if (LAYER == 0) {
        if (threadIdx.x < 32) hls[threadIdx.x] = emb_w[threadIdx.x];
    } else {
        const float* hr = hPrev + ((size_t)(node * N_CH + j)) * HPAD;
        const float4 a0 = *(const float4*)(hr);
        const float4 a1 = *(const float4*)(hr + 4);
        const float4 a2 = *(const float4*)(hr + 8);
        const float h12 = hr[12];
        const float hv[13] = {a0.x, a0.y, a0.z, a0.w, a1.x, a1.y, a1.z, a1.w,
                              a2.x, a2.y, a2.z, a2.w, h12};
#pragma unroll
        for (int m = 0; m < 13; ++m) hls[(slot * 13 + m) * 32 + j] = hv[m];
    }
    __syncthreads();

    // ================= update (streams cw/mw from HBM) =================
    float out[13];
#pragma unroll
    for (int m = 0; m < 13; ++m) out[m] = 0.f;

#pragma unroll
    for (int c = 0; c < 3; ++c) {
        const int mlo = (c == 0) ? 0 : ((c == 1) ? 1 : 4);
        const int mhi = (c == 0) ? 1 : ((c == 1) ? 4 : 13);
        const size_t wb = (((size_t)(LAYER * 3 + c) * N_NODES + node) * 32 + j) * 32;
        const float4* mwr = (const float4*)(mw + wb);
        if (LAYER == 0) {
            // h_old nonzero only at m=0 (== emb); cw[0,1],cw[0,2] multiply zeros
            if (c == 0) {
                const float4* cwr = (const float4*)(cw + wb);
#pragma unroll
                for (int k4 = 0; k4 < 8; ++k4) {
                    const float4 c4 = cwr[k4];
                    const float4 m4 = mwr[k4];
                    out[0] += dot4(c4, *(const float4*)&hls[k4 * 4])
                            + dot4(m4, *(const float4*)&mls[(slot * 13) * 32 + k4 * 4]);
                }
            } else {
#pragma unroll
                for (int k4 = 0; k4 < 8; ++k4) {
                    const float4 m4 = mwr[k4];
                    for (int m = mlo; m < mhi; ++m)
                        out[m] += dot4(m4, *(const float4*)&mls[(slot * 13 + m) * 32 + k4 * 4]);
                }
            }
        } else {
            const float4* cwr = (const float4*)(cw + wb);
#pragma unroll
            for (int k4 = 0; k4 < 8; ++k4) {
                const float4 c4 = cwr[k4];
                const float4 m4 = mwr[k4];
                for (int m = mlo; m < mhi; ++m) {
                    out[m] += dot4(c4, *(const float4*)&hls[(slot * 13 + m) * 32 + k4 * 4])
                            + dot4(m4, *(const float4*)&mls[(slot * 13 + m) * 32 + k4 * 4]);
                }
            }
        }
    }

    if (LAYER == 0) {
        // HPAD rows are 64B-aligned -> vector stores
        float* orow = hOut + ((size_t)(node * N_CH + j)) * HPAD;
        *(float4*)(orow)     = make_float4(out[0], out[1], out[2],  out[3]);
        *(float4*)(orow + 4) = make_float4(out[4], out[5], out[6],  out[7]);
        *(float4*)(orow + 8) = make_float4(out[8], out[9], out[10], out[11]);
        orow[12] = out[12];
    } else {
        float* orow = hOut + ((size_t)(node * N_CH + j)) * outStride;
#pragma unroll
        for (int m = 0; m < 13; ++m) orow[m] = out[m];
    }
}

extern "C" void kernel_launch(void* const* d_in, const int* in_sizes, int n_in,
                              void* d_out, int out_size, void* d_ws, size_t ws_size,
                              hipStream_t stream) {
    const float* pos   = (const float*)d_in[0];
    const int*   ei    = (const int*)d_in[1];
    const float* emb_w = (const float*)d_in[3];
    const float* W_ab  = (const float*)d_in[4];
    const float* ws_w  = (const float*)d_in[5];
    const float* cw    = (const float*)d_in[6];
    const float* mw    = (const float*)d_in[7];
    float* out = (float*)d_out;

    char* ws = (char*)d_ws;
    float* hB   = (float*)ws;  ws += (size_t)N_NODES * N_CH * HPAD * 4;   // 20.48 MB
    float* msgB = (float*)ws;  ws += (size_t)N_NODES * 13 * N_CH * 4;     // 16.64 MB
    float4* us4 = (float4*)ws; ws += (size_t)N_EDGES * 16;                //  2.56 MB
    int* ssrc   = (int*)ws;    ws += (size_t)N_EDGES * 4;                 //  0.64 MB
    int* offs   = (int*)ws;    ws += (size_t)(N_NODES + 16) * 4;
    int* cursor = (int*)ws;    ws += (size_t)N_NODES * 4;
    int* deg    = (int*)ws;    ws += (size_t)N_NODES * 4;

    hipMemsetAsync(deg, 0, N_NODES * 4, stream);
    k_hist<<<N_EDGES / 256, 256, 0, stream>>>(ei, deg);
    k_scan<<<1, 1024, 0, stream>>>(deg, offs, cursor);
    k_scatter<<<N_EDGES / 256, 256, 0, stream>>>(ei, pos, cursor, ssrc, us4);

    k_gather<0><<<N_NODES / SLOTS, 256, 0, stream>>>(nullptr, emb_w, ssrc, us4, offs,
                                                     W_ab, ws_w, msgB);
    k_update<0><<<N_NODES / SLOTS, 256, 0, stream>>>(nullptr, emb_w, msgB, cw, mw, hB, HPAD);
    k_gather<1><<<N_NODES / SLOTS, 256, 0, stream>>>(hB, emb_w, ssrc, us4, offs,
                                                     W_ab, ws_w, msgB);
    k_update<1><<<N_NODES / SLOTS, 256, 0, stream>>>(hB, emb_w, msgB, cw, mw, out, 13);
}

// Round 3
// 843.201 us; speedup vs baseline: 1.1258x; 1.1258x over previous
//
#include <hip/hip_runtime.h>

#define N_NODES 10000
#define N_CH    32
#define N_EDGES 160000
#define HPAD    16      // padded h row (13 used)
#define SLOTS   8       // nodes per block

__device__ __forceinline__ float dot4(float4 a, float4 b) {
    return a.x*b.x + a.y*b.y + a.z*b.z + a.w*b.w;
}

// ---------- CSR build ----------
__global__ void k_hist(const int* __restrict__ ei, int* __restrict__ deg) {
    int e = blockIdx.x * 256 + threadIdx.x;
    atomicAdd(&deg[ei[N_EDGES + e]], 1);
}

__global__ __launch_bounds__(1024) void k_scan(const int* __restrict__ deg,
                                               int* __restrict__ offs,
                                               int* __restrict__ cursor) {
    __shared__ int part[1024];
    const int t = threadIdx.x;
    const int base = t * 10;
    int s = 0;
#pragma unroll
    for (int r = 0; r < 10; ++r) { int i = base + r; if (i < N_NODES) s += deg[i]; }
    part[t] = s;
    __syncthreads();
    for (int off = 1; off < 1024; off <<= 1) {
        int v = (t >= off) ? part[t - off] : 0;
        __syncthreads();
        part[t] += v;
        __syncthreads();
    }
    int run = (t > 0) ? part[t - 1] : 0;
#pragma unroll
    for (int r = 0; r < 10; ++r) {
        int i = base + r;
        if (i < N_NODES) { offs[i] = run; cursor[i] = run; run += deg[i]; }
    }
    if (t == 0) offs[N_NODES] = N_EDGES;
}

__global__ void k_scatter(const int* __restrict__ ei, const float* __restrict__ pos,
                          int* __restrict__ cursor, int* __restrict__ ssrc,
                          float4* __restrict__ us4) {
    int e = blockIdx.x * 256 + threadIdx.x;
    int s = ei[e], d = ei[N_EDGES + e];
    float rx = pos[d*3+0] - pos[s*3+0];
    float ry = pos[d*3+1] - pos[s*3+1];
    float rz = pos[d*3+2] - pos[s*3+2];
    float inv = 1.0f / (sqrtf(rx*rx + ry*ry + rz*rz) + 1e-9f);
    int p = atomicAdd(&cursor[d], 1);
    ssrc[p] = s;
    us4[p] = make_float4(rx*inv, ry*inv, rz*inv, 0.f);
}

// ---------- gather + W-contraction + messages -> msg[N][13][32] ----------
// Symmetric-distinct basis d in 0..9: {1, x,y,z, xx,xy,xz,yy,yz,zz}
// m(0..12) -> d map: {0, 1,2,3, 4,5,6, 5,7,8, 6,8,9}
template<int LAYER>
__global__ __launch_bounds__(256, 4) void k_gather(
    const float* __restrict__ hPrev,     // [N][32][HPAD] (LAYER==1 only)
    const float* __restrict__ emb_w,     // [32]
    const int* __restrict__ ssrc,        // [E] dst-sorted src ids
    const float4* __restrict__ us4,      // [E] dst-sorted unit vectors
    const int* __restrict__ offs,        // [N+1]
    const float* __restrict__ W_ab,      // [2][3][3][32][32]
    const float* __restrict__ ws_w,      // [2][3][3][32]
    float* __restrict__ msg)             // [N][13][32]
{
    constexpr int AMAX = (LAYER == 0) ? 1 : 3;
    __shared__ __align__(16) float Tlds[SLOTS * AMAX * 10 * 32];

    const int slot = threadIdx.x >> 5;
    const int j    = threadIdx.x & 31;
    const int node = blockIdx.x * SLOTS + slot;

    const int e0 = offs[node], e1 = offs[node + 1];

    // ================= gather phase =================
    if (LAYER == 0) {
        // h0 rank-0 == emb (same every node): T0[d] = emb_j * sum_e up_d
        float U[10];
#pragma unroll
        for (int d = 0; d < 10; ++d) U[d] = 0.f;
        for (int idx = e0; idx < e1; ++idx) {
            const float4 u = us4[idx];
            U[0] += 1.f;
            U[1] += u.x;      U[2] += u.y;      U[3] += u.z;
            U[4] += u.x*u.x;  U[5] += u.x*u.y;  U[6] += u.x*u.z;
            U[7] += u.y*u.y;  U[8] += u.y*u.z;  U[9] += u.z*u.z;
        }
        const float s0 = emb_w[j];
#pragma unroll
        for (int d = 0; d < 10; ++d)
            Tlds[(slot * 10 + d) * 32 + j] = s0 * U[d];
    } else {
        float T0[10], T1[10], T2[10];
#pragma unroll
        for (int d = 0; d < 10; ++d) { T0[d] = 0.f; T1[d] = 0.f; T2[d] = 0.f; }
#pragma unroll 2
        for (int idx = e0; idx < e1; ++idx) {
            const int src = ssrc[idx];
            const float4 u = us4[idx];
            const float* hr = hPrev + ((size_t)(src * N_CH + j)) * HPAD;
            const float4 a0 = *(const float4*)(hr);
            const float4 a1 = *(const float4*)(hr + 4);
            const float4 a2 = *(const float4*)(hr + 8);
            const float h12 = hr[12];

            const float xx = u.x*u.x, xy = u.x*u.y, xz = u.x*u.z;
            const float yy = u.y*u.y, yz = u.y*u.z, zz = u.z*u.z;
            float up[10];
            up[0] = 1.f; up[1] = u.x; up[2] = u.y; up[3] = u.z;
            up[4] = xx; up[5] = xy; up[6] = xz; up[7] = yy; up[8] = yz; up[9] = zz;

            const float s0 = a0.x;
            const float s1 = a0.y*u.x + a0.z*u.y + a0.w*u.z;
            const float s2 = a1.x*xx + (a1.y + a1.w)*xy + (a1.z + a2.z)*xz
                           + a2.x*yy + (a2.y + a2.w)*yz + h12*zz;
#pragma unroll
            for (int d = 0; d < 10; ++d) {
                T0[d] += s0 * up[d];
                T1[d] += s1 * up[d];
                T2[d] += s2 * up[d];
            }
        }
#pragma unroll
        for (int d = 0; d < 10; ++d) {
            Tlds[((slot * 3 + 0) * 10 + d) * 32 + j] = T0[d];
            Tlds[((slot * 3 + 1) * 10 + d) * 32 + j] = T1[d];
            Tlds[((slot * 3 + 2) * 10 + d) * 32 + j] = T2[d];
        }
    }

    __syncthreads();   // cross-lane Tlds reads below

    // ================= W contraction (W_ab straight from L2) =================
    float acc[10];
#pragma unroll
    for (int d = 0; d < 10; ++d) acc[d] = 0.f;

#pragma unroll
    for (int c = 0; c < 3; ++c) {
        const int dlo = (c == 0) ? 0 : ((c == 1) ? 1 : 4);
        const int dhi = (c == 0) ? 1 : ((c == 1) ? 4 : 10);
#pragma unroll
        for (int a = 0; a < AMAX; ++a) {
            // W_ab[LAYER][c][a][j][0..31] — 128 B contiguous per lane, L2-resident
            const float* wrow = W_ab + (((size_t)((LAYER * 3 + c) * 3 + a)) << 10) + (j << 5);
#pragma unroll
            for (int k4 = 0; k4 < 8; ++k4) {
                const float4 w4 = *(const float4*)(wrow + k4 * 4);
                for (int d = dlo; d < dhi; ++d) {
                    const float4 t4 = *(const float4*)&Tlds[((slot * AMAX + a) * 10 + d) * 32 + k4 * 4];
                    acc[d] += dot4(w4, t4);
                }
            }
        }
    }

    // ================= messages -> global msg =================
    const float s0n = acc[0];
    const float s0sq = s0n * s0n;
    float poly[3];
#pragma unroll
    for (int c = 0; c < 3; ++c) {
        const float* wsp = ws_w + ((size_t)((LAYER * 3 + c) * 3)) * 32 + j;
        poly[c] = wsp[0] + wsp[32] * s0n + wsp[64] * s0sq;
    }
    {
        const int mExp[13] = {0, 1, 2, 3, 4, 5, 6, 5, 7, 8, 6, 8, 9};
#pragma unroll
        for (int m = 0; m < 13; ++m) {
            const float p = (m == 0) ? poly[0] : ((m < 4) ? poly[1] : poly[2]);
            msg[((size_t)node * 13 + m) * 32 + j] = p * acc[mExp[m]];
        }
    }
}

// ---------- pure streaming update: out = CW.h_old + MW.msg ----------
template<int LAYER>
__global__ __launch_bounds__(256, 4) void k_update(
    const float* __restrict__ hPrev,     // [N][32][HPAD] (LAYER==1 only)
    const float* __restrict__ emb_w,     // [32]
    const float* __restrict__ msg,       // [N][13][32]
    const float* __restrict__ cw,        // [2][3][N][32][32]
    const float* __restrict__ mw,        // [2][3][N][32][32]
    float* __restrict__ hOut)
{
    constexpr int MSZ = SLOTS * 13 * 32;          // 3328 floats
    constexpr int HSZ = (LAYER == 0) ? 32 : MSZ;
    __shared__ __align__(16) float hls[HSZ];
    __shared__ __align__(16) float mls[MSZ];

    const int slot = threadIdx.x >> 5;
    const int j    = threadIdx.x & 31;
    const int node = blockIdx.x * SLOTS + slot;

    // msg -> LDS (coalesced 128B per m per slot)
#pragma unroll
    for (int m = 0; m < 13; ++m)
        mls[(slot * 13 + m) * 32 + j] = msg[((size_t)node * 13 + m) * 32 + j];

    // h_old -> LDS
    if (LAYER == 0) {
        if (threadIdx.x < 32) hls[threadIdx.x] = emb_w[threadIdx.x];
    } else {
        const float* hr = hPrev + ((size_t)(node * N_CH + j)) * HPAD;
        const float4 a0 = *(const float4*)(hr);
        const float4 a1 = *(const float4*)(hr + 4);
        const float4 a2 = *(const float4*)(hr + 8);
        const float h12 = hr[12];
        const float hv[13] = {a0.x, a0.y, a0.z, a0.w, a1.x, a1.y, a1.z, a1.w,
                              a2.x, a2.y, a2.z, a2.w, h12};
#pragma unroll
        for (int m = 0; m < 13; ++m) hls[(slot * 13 + m) * 32 + j] = hv[m];
    }
    __syncthreads();

    // ================= update (streams cw/mw from HBM) =================
    float out[13];
#pragma unroll
    for (int m = 0; m < 13; ++m) out[m] = 0.f;

#pragma unroll
    for (int c = 0; c < 3; ++c) {
        const int mlo = (c == 0) ? 0 : ((c == 1) ? 1 : 4);
        const int mhi = (c == 0) ? 1 : ((c == 1) ? 4 : 13);
        const size_t wb = (((size_t)(LAYER * 3 + c) * N_NODES + node) * 32 + j) * 32;
        const float4* mwr = (const float4*)(mw + wb);
        if (LAYER == 0) {
            // h_old nonzero only at m=0 (== emb); cw[0,1],cw[0,2] multiply zeros
            if (c == 0) {
                const float4* cwr = (const float4*)(cw + wb);
#pragma unroll
                for (int k4 = 0; k4 < 8; ++k4) {
                    const float4 c4 = cwr[k4];
                    const float4 m4 = mwr[k4];
                    out[0] += dot4(c4, *(const float4*)&hls[k4 * 4])
                            + dot4(m4, *(const float4*)&mls[(slot * 13) * 32 + k4 * 4]);
                }
            } else {
#pragma unroll
                for (int k4 = 0; k4 < 8; ++k4) {
                    const float4 m4 = mwr[k4];
                    for (int m = mlo; m < mhi; ++m)
                        out[m] += dot4(m4, *(const float4*)&mls[(slot * 13 + m) * 32 + k4 * 4]);
                }
            }
        } else {
            const float4* cwr = (const float4*)(cw + wb);
#pragma unroll
            for (int k4 = 0; k4 < 8; ++k4) {
                const float4 c4 = cwr[k4];
                const float4 m4 = mwr[k4];
                for (int m = mlo; m < mhi; ++m) {
                    out[m] += dot4(c4, *(const float4*)&hls[(slot * 13 + m) * 32 + k4 * 4])
                            + dot4(m4, *(const float4*)&mls[(slot * 13 + m) * 32 + k4 * 4]);
                }
            }
        }
    }

    if (LAYER == 0) {
        // HPAD rows are 64B-aligned -> vector stores (full lines, no RMW)
        float* orow = hOut + ((size_t)(node * N_CH + j)) * HPAD;
        *(float4*)(orow)     = make_float4(out[0], out[1], out[2],  out[3]);
        *(float4*)(orow + 4) = make_float4(out[4], out[5], out[6],  out[7]);
        *(float4*)(orow + 8) = make_float4(out[8], out[9], out[10], out[11]);
        orow[12] = out[12];
    } else {
        // Stage out tile to LDS (reuse mls), then block-linear coalesced stores.
        // Staging writes hit only this slot's mls region, whose update-phase
        // reads were issued by the SAME wave (slot-local) -> program-order safe.
        float* ols = mls;   // viewed as [SLOTS][32][13]
#pragma unroll
        for (int m = 0; m < 13; ++m)
            ols[slot * 416 + j * 13 + m] = out[m];
        __syncthreads();
        // Block's out region: 8 consecutive nodes * 32ch * 13 = 3328 floats, contiguous
        float4* ob4 = (float4*)(hOut + (size_t)blockIdx.x * (SLOTS * N_CH * 13));
        const float4* ls4 = (const float4*)ols;
        for (int i = threadIdx.x; i < (SLOTS * N_CH * 13) / 4; i += 256)
            ob4[i] = ls4[i];   // each wave instr: 64 lanes x 16B contiguous = full lines
    }
}

extern "C" void kernel_launch(void* const* d_in, const int* in_sizes, int n_in,
                              void* d_out, int out_size, void* d_ws, size_t ws_size,
                              hipStream_t stream) {
    const float* pos   = (const float*)d_in[0];
    const int*   ei    = (const int*)d_in[1];
    const float* emb_w = (const float*)d_in[3];
    const float* W_ab  = (const float*)d_in[4];
    const float* ws_w  = (const float*)d_in[5];
    const float* cw    = (const float*)d_in[6];
    const float* mw    = (const float*)d_in[7];
    float* out = (float*)d_out;

    char* ws = (char*)d_ws;
    float* hB   = (float*)ws;  ws += (size_t)N_NODES * N_CH * HPAD * 4;   // 20.48 MB
    float* msgB = (float*)ws;  ws += (size_t)N_NODES * 13 * N_CH * 4;     // 16.64 MB
    float4* us4 = (float4*)ws; ws += (size_t)N_EDGES * 16;                //  2.56 MB
    int* ssrc   = (int*)ws;    ws += (size_t)N_EDGES * 4;                 //  0.64 MB
    int* offs   = (int*)ws;    ws += (size_t)(N_NODES + 16) * 4;
    int* cursor = (int*)ws;    ws += (size_t)N_NODES * 4;
    int* deg    = (int*)ws;    ws += (size_t)N_NODES * 4;

    hipMemsetAsync(deg, 0, N_NODES * 4, stream);
    k_hist<<<N_EDGES / 256, 256, 0, stream>>>(ei, deg);
    k_scan<<<1, 1024, 0, stream>>>(deg, offs, cursor);
    k_scatter<<<N_EDGES / 256, 256, 0, stream>>>(ei, pos, cursor, ssrc, us4);

    k_gather<0><<<N_NODES / SLOTS, 256, 0, stream>>>(nullptr, emb_w, ssrc, us4, offs,
                                                     W_ab, ws_w, msgB);
    k_update<0><<<N_NODES / SLOTS, 256, 0, stream>>>(nullptr, emb_w, msgB, cw, mw, hB);
    k_gather<1><<<N_NODES / SLOTS, 256, 0, stream>>>(hB, emb_w, ssrc, us4, offs,
                                                     W_ab, ws_w, msgB);
    k_update<1><<<N_NODES / SLOTS, 256, 0, stream>>>(hB, emb_w, msgB, cw, mw, out);
}

// Round 4
// 763.417 us; speedup vs baseline: 1.2435x; 1.1045x over previous
//
#include <hip/hip_runtime.h>

#define N_NODES 10000
#define N_CH    32
#define N_EDGES 160000
#define HPAD    16      // padded h row (13 used)
#define SLOTS   8       // nodes per block

__device__ __forceinline__ float dot4(float4 a, float4 b) {
    return a.x*b.x + a.y*b.y + a.z*b.z + a.w*b.w;
}

// ---------- CSR build ----------
__global__ void k_hist(const int* __restrict__ ei, int* __restrict__ deg) {
    int e = blockIdx.x * 256 + threadIdx.x;
    atomicAdd(&deg[ei[N_EDGES + e]], 1);
}

__global__ __launch_bounds__(1024) void k_scan(const int* __restrict__ deg,
                                               int* __restrict__ offs,
                                               int* __restrict__ cursor) {
    __shared__ int part[1024];
    const int t = threadIdx.x;
    const int base = t * 10;
    int s = 0;
#pragma unroll
    for (int r = 0; r < 10; ++r) { int i = base + r; if (i < N_NODES) s += deg[i]; }
    part[t] = s;
    __syncthreads();
    for (int off = 1; off < 1024; off <<= 1) {
        int v = (t >= off) ? part[t - off] : 0;
        __syncthreads();
        part[t] += v;
        __syncthreads();
    }
    int run = (t > 0) ? part[t - 1] : 0;
#pragma unroll
    for (int r = 0; r < 10; ++r) {
        int i = base + r;
        if (i < N_NODES) { offs[i] = run; cursor[i] = run; run += deg[i]; }
    }
    if (t == 0) offs[N_NODES] = N_EDGES;
}

__global__ void k_scatter(const int* __restrict__ ei, const float* __restrict__ pos,
                          int* __restrict__ cursor, int* __restrict__ ssrc,
                          float4* __restrict__ us4) {
    int e = blockIdx.x * 256 + threadIdx.x;
    int s = ei[e], d = ei[N_EDGES + e];
    float rx = pos[d*3+0] - pos[s*3+0];
    float ry = pos[d*3+1] - pos[s*3+1];
    float rz = pos[d*3+2] - pos[s*3+2];
    float inv = 1.0f / (sqrtf(rx*rx + ry*ry + rz*rz) + 1e-9f);
    int p = atomicAdd(&cursor[d], 1);
    ssrc[p] = s;
    us4[p] = make_float4(rx*inv, ry*inv, rz*inv, 0.f);
}

// ---------- gather + W-contraction + messages -> msg[N][13][32] ----------
// Symmetric-distinct basis d in 0..9: {1, x,y,z, xx,xy,xz,yy,yz,zz}
// m(0..12) -> d map: {0, 1,2,3, 4,5,6, 5,7,8, 6,8,9}
template<int LAYER>
__global__ __launch_bounds__(256, 2) void k_gather(
    const float* __restrict__ hPrev,     // [N][32][HPAD] (LAYER==1 only)
    const float* __restrict__ emb_w,     // [32]
    const int* __restrict__ ssrc,        // [E] dst-sorted src ids
    const float4* __restrict__ us4,      // [E] dst-sorted unit vectors
    const int* __restrict__ offs,        // [N+1]
    const float* __restrict__ W_ab,      // [2][3][3][32][32]
    const float* __restrict__ ws_w,      // [2][3][3][32]
    float* __restrict__ msg)             // [N][13][32]
{
    constexpr int AMAX = (LAYER == 0) ? 1 : 3;
    __shared__ __align__(16) float Tlds[SLOTS * AMAX * 10 * 32];

    const int slot = threadIdx.x >> 5;
    const int j    = threadIdx.x & 31;
    const int node = blockIdx.x * SLOTS + slot;

    const int e0 = offs[node], e1 = offs[node + 1];

    // ================= gather phase =================
    if (LAYER == 0) {
        // h0 rank-0 == emb (same every node): T0[d] = emb_j * sum_e up_d
        float U[10];
#pragma unroll
        for (int d = 0; d < 10; ++d) U[d] = 0.f;
        for (int idx = e0; idx < e1; ++idx) {
            const float4 u = us4[idx];
            U[0] += 1.f;
            U[1] += u.x;      U[2] += u.y;      U[3] += u.z;
            U[4] += u.x*u.x;  U[5] += u.x*u.y;  U[6] += u.x*u.z;
            U[7] += u.y*u.y;  U[8] += u.y*u.z;  U[9] += u.z*u.z;
        }
        const float s0 = emb_w[j];
#pragma unroll
        for (int d = 0; d < 10; ++d)
            Tlds[(slot * 10 + d) * 32 + j] = s0 * U[d];
    } else {
        // 30 accumulators; NO up[] temp array (was spilling 10 floats/iter)
        float T0[10], T1[10], T2[10];
#pragma unroll
        for (int d = 0; d < 10; ++d) { T0[d] = 0.f; T1[d] = 0.f; T2[d] = 0.f; }
        for (int idx = e0; idx < e1; ++idx) {
            const int src = ssrc[idx];
            const float4 u = us4[idx];
            const float* hr = hPrev + ((size_t)(src * N_CH + j)) * HPAD;
            const float4 a0 = *(const float4*)(hr);
            const float4 a1 = *(const float4*)(hr + 4);
            const float4 a2 = *(const float4*)(hr + 8);
            const float h12 = hr[12];

            const float xx = u.x*u.x, xy = u.x*u.y, xz = u.x*u.z;
            const float yy = u.y*u.y, yz = u.y*u.z, zz = u.z*u.z;

            const float s0 = a0.x;
            const float s1 = a0.y*u.x + a0.z*u.y + a0.w*u.z;
            const float s2 = a1.x*xx + (a1.y + a1.w)*xy + (a1.z + a2.z)*xz
                           + a2.x*yy + (a2.y + a2.w)*yz + h12*zz;

            // d = 0 : 1
            T0[0] += s0;       T1[0] += s1;       T2[0] += s2;
            // d = 1..3 : x,y,z
            T0[1] += s0*u.x;   T1[1] += s1*u.x;   T2[1] += s2*u.x;
            T0[2] += s0*u.y;   T1[2] += s1*u.y;   T2[2] += s2*u.y;
            T0[3] += s0*u.z;   T1[3] += s1*u.z;   T2[3] += s2*u.z;
            // d = 4..9 : xx,xy,xz,yy,yz,zz
            T0[4] += s0*xx;    T1[4] += s1*xx;    T2[4] += s2*xx;
            T0[5] += s0*xy;    T1[5] += s1*xy;    T2[5] += s2*xy;
            T0[6] += s0*xz;    T1[6] += s1*xz;    T2[6] += s2*xz;
            T0[7] += s0*yy;    T1[7] += s1*yy;    T2[7] += s2*yy;
            T0[8] += s0*yz;    T1[8] += s1*yz;    T2[8] += s2*yz;
            T0[9] += s0*zz;    T1[9] += s1*zz;    T2[9] += s2*zz;
        }
#pragma unroll
        for (int d = 0; d < 10; ++d) {
            Tlds[((slot * 3 + 0) * 10 + d) * 32 + j] = T0[d];
            Tlds[((slot * 3 + 1) * 10 + d) * 32 + j] = T1[d];
            Tlds[((slot * 3 + 2) * 10 + d) * 32 + j] = T2[d];
        }
    }

    __syncthreads();   // cross-lane Tlds reads below

    // ================= W contraction (W_ab straight from L2) =================
    float acc[10];
#pragma unroll
    for (int d = 0; d < 10; ++d) acc[d] = 0.f;

#pragma unroll
    for (int c = 0; c < 3; ++c) {
        const int dlo = (c == 0) ? 0 : ((c == 1) ? 1 : 4);
        const int dhi = (c == 0) ? 1 : ((c == 1) ? 4 : 10);
#pragma unroll
        for (int a = 0; a < AMAX; ++a) {
            // W_ab[LAYER][c][a][j][0..31] — 128 B contiguous per lane, L2-resident
            const float* wrow = W_ab + (((size_t)((LAYER * 3 + c) * 3 + a)) << 10) + (j << 5);
#pragma unroll
            for (int k4 = 0; k4 < 8; ++k4) {
                const float4 w4 = *(const float4*)(wrow + k4 * 4);
                for (int d = dlo; d < dhi; ++d) {
                    const float4 t4 = *(const float4*)&Tlds[((slot * AMAX + a) * 10 + d) * 32 + k4 * 4];
                    acc[d] += dot4(w4, t4);
                }
            }
        }
    }

    // ================= messages -> global msg =================
    const float s0n = acc[0];
    const float s0sq = s0n * s0n;
    float poly[3];
#pragma unroll
    for (int c = 0; c < 3; ++c) {
        const float* wsp = ws_w + ((size_t)((LAYER * 3 + c) * 3)) * 32 + j;
        poly[c] = wsp[0] + wsp[32] * s0n + wsp[64] * s0sq;
    }
    {
        const int mExp[13] = {0, 1, 2, 3, 4, 5, 6, 5, 7, 8, 6, 8, 9};
#pragma unroll
        for (int m = 0; m < 13; ++m) {
            const float p = (m == 0) ? poly[0] : ((m < 4) ? poly[1] : poly[2]);
            msg[((size_t)node * 13 + m) * 32 + j] = p * acc[mExp[m]];
        }
    }
}

// ---------- pure streaming update: out = CW.h_old + MW.msg ----------
template<int LAYER>
__global__ __launch_bounds__(256, 4) void k_update(
    const float* __restrict__ hPrev,     // [N][32][HPAD] (LAYER==1 only)
    const float* __restrict__ emb_w,     // [32]
    const float* __restrict__ msg,       // [N][13][32]
    const float* __restrict__ cw,        // [2][3][N][32][32]
    const float* __restrict__ mw,        // [2][3][N][32][32]
    float* __restrict__ hOut)
{
    constexpr int MSZ = SLOTS * 13 * 32;          // 3328 floats
    constexpr int HSZ = (LAYER == 0) ? 32 : MSZ;
    __shared__ __align__(16) float hls[HSZ];
    __shared__ __align__(16) float mls[MSZ];

    const int slot = threadIdx.x >> 5;
    const int j    = threadIdx.x & 31;
    const int node = blockIdx.x * SLOTS + slot;

    // msg -> LDS (coalesced 128B per m per slot)
#pragma unroll
    for (int m = 0; m < 13; ++m)
        mls[(slot * 13 + m) * 32 + j] = msg[((size_t)node * 13 + m) * 32 + j];

    // h_old -> LDS
    if (LAYER == 0) {
        if (threadIdx.x < 32) hls[threadIdx.x] = emb_w[threadIdx.x];
    } else {
        const float* hr = hPrev + ((size_t)(node * N_CH + j)) * HPAD;
        const float4 a0 = *(const float4*)(hr);
        const float4 a1 = *(const float4*)(hr + 4);
        const float4 a2 = *(const float4*)(hr + 8);
        const float h12 = hr[12];
        const float hv[13] = {a0.x, a0.y, a0.z, a0.w, a1.x, a1.y, a1.z, a1.w,
                              a2.x, a2.y, a2.z, a2.w, h12};
#pragma unroll
        for (int m = 0; m < 13; ++m) hls[(slot * 13 + m) * 32 + j] = hv[m];
    }
    __syncthreads();

    // ================= update (streams cw/mw from HBM) =================
    float out[13];
#pragma unroll
    for (int m = 0; m < 13; ++m) out[m] = 0.f;

#pragma unroll
    for (int c = 0; c < 3; ++c) {
        const int mlo = (c == 0) ? 0 : ((c == 1) ? 1 : 4);
        const int mhi = (c == 0) ? 1 : ((c == 1) ? 4 : 13);
        const size_t wb = (((size_t)(LAYER * 3 + c) * N_NODES + node) * 32 + j) * 32;
        const float4* mwr = (const float4*)(mw + wb);
        if (LAYER == 0) {
            // h_old nonzero only at m=0 (== emb); cw[0,1],cw[0,2] multiply zeros
            if (c == 0) {
                const float4* cwr = (const float4*)(cw + wb);
#pragma unroll
                for (int k4 = 0; k4 < 8; ++k4) {
                    const float4 c4 = cwr[k4];
                    const float4 m4 = mwr[k4];
                    out[0] += dot4(c4, *(const float4*)&hls[k4 * 4])
                            + dot4(m4, *(const float4*)&mls[(slot * 13) * 32 + k4 * 4]);
                }
            } else {
#pragma unroll
                for (int k4 = 0; k4 < 8; ++k4) {
                    const float4 m4 = mwr[k4];
                    for (int m = mlo; m < mhi; ++m)
                        out[m] += dot4(m4, *(const float4*)&mls[(slot * 13 + m) * 32 + k4 * 4]);
                }
            }
        } else {
            const float4* cwr = (const float4*)(cw + wb);
#pragma unroll
            for (int k4 = 0; k4 < 8; ++k4) {
                const float4 c4 = cwr[k4];
                const float4 m4 = mwr[k4];
                for (int m = mlo; m < mhi; ++m) {
                    out[m] += dot4(c4, *(const float4*)&hls[(slot * 13 + m) * 32 + k4 * 4])
                            + dot4(m4, *(const float4*)&mls[(slot * 13 + m) * 32 + k4 * 4]);
                }
            }
        }
    }

    if (LAYER == 0) {
        // HPAD rows are 64B-aligned -> vector stores (full lines, no RMW)
        float* orow = hOut + ((size_t)(node * N_CH + j)) * HPAD;
        *(float4*)(orow)     = make_float4(out[0], out[1], out[2],  out[3]);
        *(float4*)(orow + 4) = make_float4(out[4], out[5], out[6],  out[7]);
        *(float4*)(orow + 8) = make_float4(out[8], out[9], out[10], out[11]);
        orow[12] = out[12];
    } else {
        // Stage out tile to LDS (reuse mls), then block-linear coalesced stores.
        // Staging writes hit only this slot's mls region, whose update-phase
        // reads were issued by the SAME wave (slot-local) -> program-order safe.
        float* ols = mls;   // viewed as [SLOTS][32][13]
#pragma unroll
        for (int m = 0; m < 13; ++m)
            ols[slot * 416 + j * 13 + m] = out[m];
        __syncthreads();
        // Block's out region: 8 consecutive nodes * 32ch * 13 = 3328 floats, contiguous
        float4* ob4 = (float4*)(hOut + (size_t)blockIdx.x * (SLOTS * N_CH * 13));
        const float4* ls4 = (const float4*)ols;
        for (int i = threadIdx.x; i < (SLOTS * N_CH * 13) / 4; i += 256)
            ob4[i] = ls4[i];   // each wave instr: 64 lanes x 16B contiguous = full lines
    }
}

extern "C" void kernel_launch(void* const* d_in, const int* in_sizes, int n_in,
                              void* d_out, int out_size, void* d_ws, size_t ws_size,
                              hipStream_t stream) {
    const float* pos   = (const float*)d_in[0];
    const int*   ei    = (const int*)d_in[1];
    const float* emb_w = (const float*)d_in[3];
    const float* W_ab  = (const float*)d_in[4];
    const float* ws_w  = (const float*)d_in[5];
    const float* cw    = (const float*)d_in[6];
    const float* mw    = (const float*)d_in[7];
    float* out = (float*)d_out;

    char* ws = (char*)d_ws;
    float* hB   = (float*)ws;  ws += (size_t)N_NODES * N_CH * HPAD * 4;   // 20.48 MB
    float* msgB = (float*)ws;  ws += (size_t)N_NODES * 13 * N_CH * 4;     // 16.64 MB
    float4* us4 = (float4*)ws; ws += (size_t)N_EDGES * 16;                //  2.56 MB
    int* ssrc   = (int*)ws;    ws += (size_t)N_EDGES * 4;                 //  0.64 MB
    int* offs   = (int*)ws;    ws += (size_t)(N_NODES + 16) * 4;
    int* cursor = (int*)ws;    ws += (size_t)N_NODES * 4;
    int* deg    = (int*)ws;    ws += (size_t)N_NODES * 4;

    hipMemsetAsync(deg, 0, N_NODES * 4, stream);
    k_hist<<<N_EDGES / 256, 256, 0, stream>>>(ei, deg);
    k_scan<<<1, 1024, 0, stream>>>(deg, offs, cursor);
    k_scatter<<<N_EDGES / 256, 256, 0, stream>>>(ei, pos, cursor, ssrc, us4);

    k_gather<0><<<N_NODES / SLOTS, 256, 0, stream>>>(nullptr, emb_w, ssrc, us4, offs,
                                                     W_ab, ws_w, msgB);
    k_update<0><<<N_NODES / SLOTS, 256, 0, stream>>>(nullptr, emb_w, msgB, cw, mw, hB);
    k_gather<1><<<N_NODES / SLOTS, 256, 0, stream>>>(hB, emb_w, ssrc, us4, offs,
                                                     W_ab, ws_w, msgB);
    k_update<1><<<N_NODES / SLOTS, 256, 0, stream>>>(hB, emb_w, msgB, cw, mw, out);
}

// Round 10
// 698.935 us; speedup vs baseline: 1.3582x; 1.0923x over previous
//
#include <hip/hip_runtime.h>

#define N_NODES 10000
#define N_CH    32
#define N_EDGES 160000
#define HPAD    16      // padded h row (13 used)
#define SLOTS   8       // nodes per block

__device__ __forceinline__ float dot4(float4 a, float4 b) {
    return a.x*b.x + a.y*b.y + a.z*b.z + a.w*b.w;
}

// ---------- CSR build ----------
__global__ void k_hist(const int* __restrict__ ei, int* __restrict__ deg) {
    int e = blockIdx.x * 256 + threadIdx.x;
    atomicAdd(&deg[ei[N_EDGES + e]], 1);
}

__global__ __launch_bounds__(1024) void k_scan(const int* __restrict__ deg,
                                               int* __restrict__ offs,
                                               int* __restrict__ cursor) {
    __shared__ int part[1024];
    const int t = threadIdx.x;
    const int base = t * 10;
    int s = 0;
#pragma unroll
    for (int r = 0; r < 10; ++r) { int i = base + r; if (i < N_NODES) s += deg[i]; }
    part[t] = s;
    __syncthreads();
    for (int off = 1; off < 1024; off <<= 1) {
        int v = (t >= off) ? part[t - off] : 0;
        __syncthreads();
        part[t] += v;
        __syncthreads();
    }
    int run = (t > 0) ? part[t - 1] : 0;
#pragma unroll
    for (int r = 0; r < 10; ++r) {
        int i = base + r;
        if (i < N_NODES) { offs[i] = run; cursor[i] = run; run += deg[i]; }
    }
    if (t == 0) offs[N_NODES] = N_EDGES;
}

__global__ void k_scatter(const int* __restrict__ ei, const float* __restrict__ pos,
                          int* __restrict__ cursor, int* __restrict__ ssrc,
                          float4* __restrict__ us4) {
    int e = blockIdx.x * 256 + threadIdx.x;
    int s = ei[e], d = ei[N_EDGES + e];
    float rx = pos[d*3+0] - pos[s*3+0];
    float ry = pos[d*3+1] - pos[s*3+1];
    float rz = pos[d*3+2] - pos[s*3+2];
    float inv = 1.0f / (sqrtf(rx*rx + ry*ry + rz*rz) + 1e-9f);
    int p = atomicAdd(&cursor[d], 1);
    ssrc[p] = s;
    us4[p] = make_float4(rx*inv, ry*inv, rz*inv, 0.f);
}

// ---------- gather + W-contraction + messages -> msg[N][13][32] ----------
// Symmetric-distinct basis d in 0..9: {1, x,y,z, xx,xy,xz,yy,yz,zz}
// m(0..12) -> d map: {0, 1,2,3, 4,5,6, 5,7,8, 6,8,9}
template<int LAYER>
__global__ __launch_bounds__(256, 2) void k_gather(
    const float* __restrict__ hPrev,     // [N][32][HPAD] (LAYER==1 only)
    const float* __restrict__ emb_w,     // [32]
    const int* __restrict__ ssrc,        // [E] dst-sorted src ids
    const float4* __restrict__ us4,      // [E] dst-sorted unit vectors
    const int* __restrict__ offs,        // [N+1]
    const float* __restrict__ W_ab,      // [2][3][3][32][32]
    const float* __restrict__ ws_w,      // [2][3][3][32]
    float* __restrict__ msg)             // [N][13][32]
{
    constexpr int AMAX = (LAYER == 0) ? 1 : 3;
    __shared__ __align__(16) float Tlds[SLOTS * AMAX * 10 * 32];

    const int slot = threadIdx.x >> 5;
    const int j    = threadIdx.x & 31;
    const int node = blockIdx.x * SLOTS + slot;

    const int e0 = offs[node], e1 = offs[node + 1];

    // ================= gather phase =================
    if (LAYER == 0) {
        // h0 rank-0 == emb (same every node): T0[d] = emb_j * sum_e up_d
        float U[10];
#pragma unroll
        for (int d = 0; d < 10; ++d) U[d] = 0.f;
        for (int idx = e0; idx < e1; ++idx) {
            const float4 u = us4[idx];
            U[0] += 1.f;
            U[1] += u.x;      U[2] += u.y;      U[3] += u.z;
            U[4] += u.x*u.x;  U[5] += u.x*u.y;  U[6] += u.x*u.z;
            U[7] += u.y*u.y;  U[8] += u.y*u.z;  U[9] += u.z*u.z;
        }
        const float s0 = emb_w[j];
#pragma unroll
        for (int d = 0; d < 10; ++d)
            Tlds[(slot * 10 + d) * 32 + j] = s0 * U[d];
    } else {
        // 30 accumulators; NO up[] temp array (was spilling 10 floats/iter)
        float T0[10], T1[10], T2[10];
#pragma unroll
        for (int d = 0; d < 10; ++d) { T0[d] = 0.f; T1[d] = 0.f; T2[d] = 0.f; }
        for (int idx = e0; idx < e1; ++idx) {
            const int src = ssrc[idx];
            const float4 u = us4[idx];
            const float* hr = hPrev + ((size_t)(src * N_CH + j)) * HPAD;
            const float4 a0 = *(const float4*)(hr);
            const float4 a1 = *(const float4*)(hr + 4);
            const float4 a2 = *(const float4*)(hr + 8);
            const float h12 = hr[12];

            const float xx = u.x*u.x, xy = u.x*u.y, xz = u.x*u.z;
            const float yy = u.y*u.y, yz = u.y*u.z, zz = u.z*u.z;

            const float s0 = a0.x;
            const float s1 = a0.y*u.x + a0.z*u.y + a0.w*u.z;
            const float s2 = a1.x*xx + (a1.y + a1.w)*xy + (a1.z + a2.z)*xz
                           + a2.x*yy + (a2.y + a2.w)*yz + h12*zz;

            T0[0] += s0;       T1[0] += s1;       T2[0] += s2;
            T0[1] += s0*u.x;   T1[1] += s1*u.x;   T2[1] += s2*u.x;
            T0[2] += s0*u.y;   T1[2] += s1*u.y;   T2[2] += s2*u.y;
            T0[3] += s0*u.z;   T1[3] += s1*u.z;   T2[3] += s2*u.z;
            T0[4] += s0*xx;    T1[4] += s1*xx;    T2[4] += s2*xx;
            T0[5] += s0*xy;    T1[5] += s1*xy;    T2[5] += s2*xy;
            T0[6] += s0*xz;    T1[6] += s1*xz;    T2[6] += s2*xz;
            T0[7] += s0*yy;    T1[7] += s1*yy;    T2[7] += s2*yy;
            T0[8] += s0*yz;    T1[8] += s1*yz;    T2[8] += s2*yz;
            T0[9] += s0*zz;    T1[9] += s1*zz;    T2[9] += s2*zz;
        }
#pragma unroll
        for (int d = 0; d < 10; ++d) {
            Tlds[((slot * 3 + 0) * 10 + d) * 32 + j] = T0[d];
            Tlds[((slot * 3 + 1) * 10 + d) * 32 + j] = T1[d];
            Tlds[((slot * 3 + 2) * 10 + d) * 32 + j] = T2[d];
        }
    }

    __syncthreads();   // cross-lane Tlds reads below

    // ================= W contraction (W_ab straight from L2) =================
    float acc[10];
#pragma unroll
    for (int d = 0; d < 10; ++d) acc[d] = 0.f;

#pragma unroll
    for (int c = 0; c < 3; ++c) {
        const int dlo = (c == 0) ? 0 : ((c == 1) ? 1 : 4);
        const int dhi = (c == 0) ? 1 : ((c == 1) ? 4 : 10);
#pragma unroll
        for (int a = 0; a < AMAX; ++a) {
            // W_ab[LAYER][c][a][j][0..31] — 128 B contiguous per lane, L2-resident
            const float* wrow = W_ab + (((size_t)((LAYER * 3 + c) * 3 + a)) << 10) + (j << 5);
#pragma unroll
            for (int k4 = 0; k4 < 8; ++k4) {
                const float4 w4 = *(const float4*)(wrow + k4 * 4);
                for (int d = dlo; d < dhi; ++d) {
                    const float4 t4 = *(const float4*)&Tlds[((slot * AMAX + a) * 10 + d) * 32 + k4 * 4];
                    acc[d] += dot4(w4, t4);
                }
            }
        }
    }

    // ================= messages -> global msg =================
    const float s0n = acc[0];
    const float s0sq = s0n * s0n;
    float poly[3];
#pragma unroll
    for (int c = 0; c < 3; ++c) {
        const float* wsp = ws_w + ((size_t)((LAYER * 3 + c) * 3)) * 32 + j;
        poly[c] = wsp[0] + wsp[32] * s0n + wsp[64] * s0sq;
    }
    {
        const int mExp[13] = {0, 1, 2, 3, 4, 5, 6, 5, 7, 8, 6, 8, 9};
#pragma unroll
        for (int m = 0; m < 13; ++m) {
            const float p = (m == 0) ? poly[0] : ((m < 4) ? poly[1] : poly[2]);
            msg[((size_t)node * 13 + m) * 32 + j] = p * acc[mExp[m]];
        }
    }
}

// ---------- pure streaming update: out = CW.h_old + MW.msg ----------
// Coalesced weight consumption: lane l of a slot loads slab chunk [q*128+l*4]
// (32 lanes x 16B = 512B contiguous per instr, each HBM line referenced ONCE).
// Lane l holds rows 4q+l/8, col chunk l%8; 3-step shfl_xor butterfly over the
// 8 col-chunk lanes finishes the 32-wide dot; group leader writes ols[row][m].
template<int LAYER>
__global__ __launch_bounds__(256, 4) void k_update(
    const float* __restrict__ hPrev,     // [N][32][HPAD] (LAYER==1 only)
    const float* __restrict__ emb_w,     // [32]
    const float* __restrict__ msg,       // [N][13][32]
    const float* __restrict__ cw,        // [2][3][N][32][32]
    const float* __restrict__ mw,        // [2][3][N][32][32]
    float* __restrict__ hOut)
{
    constexpr int MSZ = SLOTS * 13 * 32;          // 3328 floats
    constexpr int HSZ = (LAYER == 0) ? 32 : MSZ;
    constexpr int OSZ = SLOTS * 32 * 13;          // out accumulator [SLOTS][32ch][13m]
    __shared__ __align__(16) float hls[HSZ];
    __shared__ __align__(16) float mls[MSZ];
    __shared__ __align__(16) float ols[OSZ];

    const int slot = threadIdx.x >> 5;
    const int l    = threadIdx.x & 31;
    const int node = blockIdx.x * SLOTS + slot;
    const int g    = l >> 3;     // row group 0..3
    const int cl   = l & 7;      // col chunk 0..7

    // msg -> LDS (coalesced 128B per m per slot)
#pragma unroll
    for (int m = 0; m < 13; ++m)
        mls[(slot * 13 + m) * 32 + l] = msg[((size_t)node * 13 + m) * 32 + l];

    // h_old -> LDS
    if (LAYER == 0) {
        if (threadIdx.x < 32) hls[threadIdx.x] = emb_w[threadIdx.x];
    } else {
        const float* hr = hPrev + ((size_t)(node * N_CH + l)) * HPAD;
        const float4 a0 = *(const float4*)(hr);
        const float4 a1 = *(const float4*)(hr + 4);
        const float4 a2 = *(const float4*)(hr + 8);
        const float h12 = hr[12];
        const float hv[13] = {a0.x, a0.y, a0.z, a0.w, a1.x, a1.y, a1.z, a1.w,
                              a2.x, a2.y, a2.z, a2.w, h12};
#pragma unroll
        for (int m = 0; m < 13; ++m) hls[(slot * 13 + m) * 32 + l] = hv[m];
    }
    __syncthreads();

    // ================= compute: ols[ch][m] = cw_row.h[m] + mw_row.msg[m] ======
#pragma unroll
    for (int c = 0; c < 3; ++c) {
        const int mlo = (c == 0) ? 0 : ((c == 1) ? 1 : 4);
        const int mhi = (c == 0) ? 1 : ((c == 1) ? 4 : 13);
        const bool useC = (LAYER == 1) || (c == 0);
        const size_t slabBase = ((size_t)(LAYER * 3 + c) * N_NODES + node) * 1024;
        const float* cwS = cw + slabBase;
        const float* mwS = mw + slabBase;
#pragma unroll
        for (int q = 0; q < 8; ++q) {
            const int off = q * 128 + l * 4;
            const float4 m4 = *(const float4*)(mwS + off);
            float4 c4 = make_float4(0.f, 0.f, 0.f, 0.f);
            if (useC) c4 = *(const float4*)(cwS + off);
            const int row = 4 * q + g;
            for (int m = mlo; m < mhi; ++m) {
                const float4 v4 = *(const float4*)&mls[(slot * 13 + m) * 32 + cl * 4];
                float p = dot4(m4, v4);
                if (useC) {
                    const float4 h4 = (LAYER == 0)
                        ? *(const float4*)&hls[cl * 4]
                        : *(const float4*)&hls[(slot * 13 + m) * 32 + cl * 4];
                    p += dot4(c4, h4);
                }
                p += __shfl_xor(p, 1);
                p += __shfl_xor(p, 2);
                p += __shfl_xor(p, 4);
                if (cl == 0) ols[(slot * 32 + row) * 13 + m] = p;
            }
        }
    }
    __syncthreads();

    // ================= store =================
    if (LAYER == 0) {
        // lane l = channel; HPAD rows 64B-aligned -> vector stores
        float o[13];
#pragma unroll
        for (int m = 0; m < 13; ++m) o[m] = ols[(slot * 32 + l) * 13 + m];
        float* orow = hOut + ((size_t)(node * N_CH + l)) * HPAD;
        *(float4*)(orow)     = make_float4(o[0], o[1], o[2],  o[3]);
        *(float4*)(orow + 4) = make_float4(o[4], o[5], o[6],  o[7]);
        *(float4*)(orow + 8) = make_float4(o[8], o[9], o[10], o[11]);
        orow[12] = o[12];
    } else {
        // ols layout [8 nodes][32 ch][13] == hOut block region, contiguous
        float4* ob4 = (float4*)(hOut + (size_t)blockIdx.x * (SLOTS * N_CH * 13));
        const float4* ls4 = (const float4*)ols;
        for (int i = threadIdx.x; i < (SLOTS * N_CH * 13) / 4; i += 256)
            ob4[i] = ls4[i];   // each wave instr: 64 lanes x 16B contiguous = full lines
    }
}

extern "C" void kernel_launch(void* const* d_in, const int* in_sizes, int n_in,
                              void* d_out, int out_size, void* d_ws, size_t ws_size,
                              hipStream_t stream) {
    const float* pos   = (const float*)d_in[0];
    const int*   ei    = (const int*)d_in[1];
    const float* emb_w = (const float*)d_in[3];
    const float* W_ab  = (const float*)d_in[4];
    const float* ws_w  = (const float*)d_in[5];
    const float* cw    = (const float*)d_in[6];
    const float* mw    = (const float*)d_in[7];
    float* out = (float*)d_out;

    char* ws = (char*)d_ws;
    float* hB   = (float*)ws;  ws += (size_t)N_NODES * N_CH * HPAD * 4;   // 20.48 MB
    float* msgB = (float*)ws;  ws += (size_t)N_NODES * 13 * N_CH * 4;     // 16.64 MB
    float4* us4 = (float4*)ws; ws += (size_t)N_EDGES * 16;                //  2.56 MB
    int* ssrc   = (int*)ws;    ws += (size_t)N_EDGES * 4;                 //  0.64 MB
    int* offs   = (int*)ws;    ws += (size_t)(N_NODES + 16) * 4;
    int* cursor = (int*)ws;    ws += (size_t)N_NODES * 4;
    int* deg    = (int*)ws;    ws += (size_t)N_NODES * 4;

    hipMemsetAsync(deg, 0, N_NODES * 4, stream);
    k_hist<<<N_EDGES / 256, 256, 0, stream>>>(ei, deg);
    k_scan<<<1, 1024, 0, stream>>>(deg, offs, cursor);
    k_scatter<<<N_EDGES / 256, 256, 0, stream>>>(ei, pos, cursor, ssrc, us4);

    k_gather<0><<<N_NODES / SLOTS, 256, 0, stream>>>(nullptr, emb_w, ssrc, us4, offs,
                                                     W_ab, ws_w, msgB);
    k_update<0><<<N_NODES / SLOTS, 256, 0, stream>>>(nullptr, emb_w, msgB, cw, mw, hB);
    k_gather<1><<<N_NODES / SLOTS, 256, 0, stream>>>(hB, emb_w, ssrc, us4, offs,
                                                     W_ab, ws_w, msgB);
    k_update<1><<<N_NODES / SLOTS, 256, 0, stream>>>(hB, emb_w, msgB, cw, mw, out);
}